// Round 1
// baseline (386.194 us; speedup 1.0000x reference)
//
#include <hip/hip_runtime.h>
#include <stdint.h>

typedef unsigned short u16;
typedef __attribute__((ext_vector_type(8))) __bf16 bf16x8;
typedef __attribute__((ext_vector_type(4))) float f32x4;

#define SEQL 2048
#define NHEADS 16
#define HDIM 64
#define BSZ 4
#define EMB 1024
#define MROWS (BSZ * SEQL) /* 8192 */

__device__ __forceinline__ u16 f2bf(float f) {
  union { float f; uint32_t u; } v; v.f = f;
  return (u16)((v.u + 0x7fffu + ((v.u >> 16) & 1u)) >> 16);
}

__device__ __forceinline__ void gload_lds16(const u16* g, u16* l) {
  __builtin_amdgcn_global_load_lds(
      (__attribute__((address_space(1))) void*)(g),
      (__attribute__((address_space(3))) void*)(l), 16, 0, 0);
}

__device__ __forceinline__ void cvt8(const float* __restrict__ in, u16* __restrict__ out, int i) {
  float4 a = *(const float4*)(in + i);
  float4 b = *(const float4*)(in + i + 4);
  uint4 o;
  o.x = f2bf(a.x) | ((uint32_t)f2bf(a.y) << 16);
  o.y = f2bf(a.z) | ((uint32_t)f2bf(a.w) << 16);
  o.z = f2bf(b.x) | ((uint32_t)f2bf(b.y) << 16);
  o.w = f2bf(b.z) | ((uint32_t)f2bf(b.w) << 16);
  *(uint4*)(out + i) = o;
}

// ---------------- fp32 -> bf16 conversions ----------------
__global__ void cvt_kernel(const float* __restrict__ in, u16* __restrict__ out, int n) {
  int i = (blockIdx.x * blockDim.x + threadIdx.x) * 8;
  if (i + 8 <= n) cvt8(in, out, i);
}

__global__ void cvt_w4(const float* __restrict__ w0, const float* __restrict__ w1,
                       const float* __restrict__ w2, const float* __restrict__ w3,
                       u16* __restrict__ o0, u16* __restrict__ o1,
                       u16* __restrict__ o2, u16* __restrict__ o3) {
  const float* in = blockIdx.y == 0 ? w0 : blockIdx.y == 1 ? w1 : blockIdx.y == 2 ? w2 : w3;
  u16* out = blockIdx.y == 0 ? o0 : blockIdx.y == 1 ? o1 : blockIdx.y == 2 ? o2 : o3;
  int i = (blockIdx.x * blockDim.x + threadIdx.x) * 8;
  cvt8(in, out, i);
}

// ---------------- GEMM core: C[128x128] = A[128xK] * B[128xK]^T  (both row-major, K=1024)
// m97 structure: BK=32, 4 waves (2x2), global_load_lds width 16, 16x16x32 bf16 MFMA.
__device__ __forceinline__ void gemm_core(const u16* __restrict__ A, const u16* __restrict__ B,
                                          int m0, int n0, u16* As, u16* Bs, f32x4 acc[4][4]) {
  const int tid = threadIdx.x;
  const int lane = tid & 63;
  const int wid = tid >> 6;
  const int wm = wid >> 1, wn = wid & 1;
  const int srow = lane >> 2;          // 0..15
  const int scol = (lane & 3) * 8;     // element offset (16B chunks)
  const int lrow = lane & 15;
  const int kg = (lane >> 4) * 8;

  const u16* Ag0 = A + (size_t)(m0 + wid * 32 + srow) * EMB + scol;
  const u16* Bg0 = B + (size_t)(n0 + wid * 32 + srow) * EMB + scol;
  u16* Al0 = As + (wid * 32 + srow) * 32 + scol;   // linear [128][32], lane-ordered per wave
  u16* Bl0 = Bs + (wid * 32 + srow) * 32 + scol;

  for (int k0 = 0; k0 < EMB; k0 += 32) {
    gload_lds16(Ag0 + k0, Al0);
    gload_lds16(Ag0 + k0 + 16 * EMB, Al0 + 16 * 32);
    gload_lds16(Bg0 + k0, Bl0);
    gload_lds16(Bg0 + k0 + 16 * EMB, Bl0 + 16 * 32);
    __syncthreads();
    bf16x8 af[4], bfr[4];
#pragma unroll
    for (int f = 0; f < 4; ++f) {
      af[f]  = *(const bf16x8*)(As + (wm * 64 + f * 16 + lrow) * 32 + kg);
      bfr[f] = *(const bf16x8*)(Bs + (wn * 64 + f * 16 + lrow) * 32 + kg);
    }
#pragma unroll
    for (int fm = 0; fm < 4; ++fm)
#pragma unroll
      for (int fn = 0; fn < 4; ++fn)
        acc[fm][fn] = __builtin_amdgcn_mfma_f32_16x16x32_bf16(af[fm], bfr[fn], acc[fm][fn], 0, 0, 0);
    __syncthreads();
  }
}

// QKV projection: one launch, blockIdx.y selects {Q,K,V}. Output bf16 in [b,h,s,d] layout.
__global__ __launch_bounds__(256, 2) void gemm_qkv(
    const u16* __restrict__ X,
    const u16* __restrict__ Wq, const u16* __restrict__ Wk, const u16* __restrict__ Wv,
    const float* __restrict__ bq, const float* __restrict__ bk, const float* __restrict__ bv,
    u16* __restrict__ Qb, u16* __restrict__ Kb, u16* __restrict__ Vb) {
  __shared__ u16 As[128 * 32];
  __shared__ u16 Bs[128 * 32];
  const int which = blockIdx.y;
  const u16* W = which == 0 ? Wq : which == 1 ? Wk : Wv;
  const float* bias = which == 0 ? bq : which == 1 ? bk : bv;
  u16* Ob = which == 0 ? Qb : which == 1 ? Kb : Vb;
  const float scale = which == 0 ? 0.125f : 1.0f;

  const int mt = blockIdx.x >> 3, nt = blockIdx.x & 7;
  const f32x4 fzero = {0.f, 0.f, 0.f, 0.f};
  f32x4 acc[4][4];
#pragma unroll
  for (int i = 0; i < 4; ++i)
#pragma unroll
    for (int j = 0; j < 4; ++j) acc[i][j] = fzero;

  gemm_core(X, W, mt * 128, nt * 128, As, Bs, acc);

  const int lane = threadIdx.x & 63;
  const int wid = threadIdx.x >> 6;
  const int wm = wid >> 1, wn = wid & 1;
  const int lrow = lane & 15, g = lane >> 4;
#pragma unroll
  for (int fm = 0; fm < 4; ++fm)
#pragma unroll
    for (int fn = 0; fn < 4; ++fn) {
      int n = nt * 128 + wn * 64 + fn * 16 + lrow;
      float bs = bias[n];
      int h = n >> 6, d = n & 63;
#pragma unroll
      for (int r = 0; r < 4; ++r) {
        int m = mt * 128 + wm * 64 + fm * 16 + g * 4 + r;
        int b = m >> 11, s = m & 2047;
        float v = (acc[fm][fn][r] + bs) * scale;
        Ob[(size_t)((b * NHEADS + h) * SEQL + s) * HDIM + d] = f2bf(v);
      }
    }
}

// Output projection: fp32 result
__global__ __launch_bounds__(256, 2) void gemm_out(
    const u16* __restrict__ Ain, const u16* __restrict__ Wo,
    const float* __restrict__ bo, float* __restrict__ out) {
  __shared__ u16 As[128 * 32];
  __shared__ u16 Bs[128 * 32];
  const int mt = blockIdx.x >> 3, nt = blockIdx.x & 7;
  const f32x4 fzero = {0.f, 0.f, 0.f, 0.f};
  f32x4 acc[4][4];
#pragma unroll
  for (int i = 0; i < 4; ++i)
#pragma unroll
    for (int j = 0; j < 4; ++j) acc[i][j] = fzero;

  gemm_core(Ain, Wo, mt * 128, nt * 128, As, Bs, acc);

  const int lane = threadIdx.x & 63;
  const int wid = threadIdx.x >> 6;
  const int wm = wid >> 1, wn = wid & 1;
  const int lrow = lane & 15, g = lane >> 4;
#pragma unroll
  for (int fm = 0; fm < 4; ++fm)
#pragma unroll
    for (int fn = 0; fn < 4; ++fn) {
      int n = nt * 128 + wn * 64 + fn * 16 + lrow;
      float bs = bo[n];
#pragma unroll
      for (int r = 0; r < 4; ++r) {
        int m = mt * 128 + wm * 64 + fm * 16 + g * 4 + r;
        out[(size_t)m * EMB + n] = acc[fm][fn][r] + bs;
      }
    }
}

// ---------------- causal flash attention ----------------
// grid (32 qtiles, 64 bh), 256 threads. Per wave: 16 q-rows. KV-tile = 64.
__global__ __launch_bounds__(256, 2) void attn_kernel(
    const u16* __restrict__ Qb, const u16* __restrict__ Kb, const u16* __restrict__ Vb,
    u16* __restrict__ Ab) {
  __shared__ u16 Ks[64 * 72];      // K rows [kv][d], stride 72
  __shared__ u16 Vt[64 * 72];      // V transposed [d][kv], stride 72
  __shared__ u16 Ps[4][16 * 72];   // per-wave P tile [q][kv], stride 72

  const int qt = blockIdx.x, bh = blockIdx.y;
  const int q0 = qt * 64;
  const int tid = threadIdx.x, lane = tid & 63, wid = tid >> 6;
  const int lrow = lane & 15, g = lane >> 4, kg = g * 8;

  const u16* Qbh = Qb + (size_t)bh * SEQL * HDIM;
  const u16* Kbh = Kb + (size_t)bh * SEQL * HDIM;
  const u16* Vbh = Vb + (size_t)bh * SEQL * HDIM;

  // Q fragments for this wave's 16 rows (already scaled by 1/8 in projection)
  bf16x8 qf0 = *(const bf16x8*)(Qbh + (size_t)(q0 + wid * 16 + lrow) * HDIM + kg);
  bf16x8 qf1 = *(const bf16x8*)(Qbh + (size_t)(q0 + wid * 16 + lrow) * HDIM + 32 + kg);

  const f32x4 fzero = {0.f, 0.f, 0.f, 0.f};
  float m_run[4], l_run[4];
  f32x4 accO[4];
#pragma unroll
  for (int r = 0; r < 4; ++r) { m_run[r] = -1e30f; l_run[r] = 0.f; }
#pragma unroll
  for (int d = 0; d < 4; ++d) accO[d] = fzero;

  const int srow = tid >> 3;         // staging row 0..31 (+32 on 2nd chunk)
  const int scc = (tid & 7) * 8;     // staging col chunk

  for (int kv0 = 0; kv0 <= q0; kv0 += 64) {
#pragma unroll
    for (int i = 0; i < 2; ++i) {
      int row = srow + i * 32;
      uint4 kk = *(const uint4*)(Kbh + (size_t)(kv0 + row) * HDIM + scc);
      *(uint4*)(Ks + row * 72 + scc) = kk;
      uint4 vv = *(const uint4*)(Vbh + (size_t)(kv0 + row) * HDIM + scc);
      const u16* pv = (const u16*)&vv;
#pragma unroll
      for (int e = 0; e < 8; ++e) Vt[(scc + e) * 72 + row] = pv[e];
    }
    __syncthreads();

    // S = Q K^T  (D layout: col=lane&15 -> kv col, row=g*4+r -> q row)
    f32x4 sacc[4];
#pragma unroll
    for (int kb = 0; kb < 4; ++kb) {
      bf16x8 kf0 = *(const bf16x8*)(Ks + (kb * 16 + lrow) * 72 + kg);
      bf16x8 kf1 = *(const bf16x8*)(Ks + (kb * 16 + lrow) * 72 + 32 + kg);
      f32x4 z = fzero;
      z = __builtin_amdgcn_mfma_f32_16x16x32_bf16(qf0, kf0, z, 0, 0, 0);
      z = __builtin_amdgcn_mfma_f32_16x16x32_bf16(qf1, kf1, z, 0, 0, 0);
      sacc[kb] = z;
    }

    if (kv0 == q0) {  // only diagonal tile needs the causal mask
#pragma unroll
      for (int kb = 0; kb < 4; ++kb) {
        int kc = kb * 16 + lrow;
#pragma unroll
        for (int r = 0; r < 4; ++r)
          if (kc > wid * 16 + g * 4 + r) sacc[kb][r] = -1e30f;
      }
    }

    // online softmax; row owned by 16-lane group (xor 1,2,4,8)
#pragma unroll
    for (int r = 0; r < 4; ++r) {
      float mx = fmaxf(fmaxf(sacc[0][r], sacc[1][r]), fmaxf(sacc[2][r], sacc[3][r]));
      mx = fmaxf(mx, __shfl_xor(mx, 1));
      mx = fmaxf(mx, __shfl_xor(mx, 2));
      mx = fmaxf(mx, __shfl_xor(mx, 4));
      mx = fmaxf(mx, __shfl_xor(mx, 8));
      float mnew = fmaxf(m_run[r], mx);
      float sc = __expf(m_run[r] - mnew);
      m_run[r] = mnew;
      l_run[r] *= sc;
#pragma unroll
      for (int d = 0; d < 4; ++d) accO[d][r] *= sc;
#pragma unroll
      for (int kb = 0; kb < 4; ++kb) {
        float p = __expf(sacc[kb][r] - mnew);
        l_run[r] += p;   // per-lane partial; reduced at the end
        Ps[wid][(g * 4 + r) * 72 + kb * 16 + lrow] = f2bf(p);
      }
    }

    // PV: A = P (rows=q), B = V^T rows (cols=dout)
#pragma unroll
    for (int ks = 0; ks < 2; ++ks) {
      bf16x8 pf = *(const bf16x8*)(Ps[wid] + lrow * 72 + ks * 32 + kg);
#pragma unroll
      for (int d = 0; d < 4; ++d) {
        bf16x8 vf = *(const bf16x8*)(Vt + (d * 16 + lrow) * 72 + ks * 32 + kg);
        accO[d] = __builtin_amdgcn_mfma_f32_16x16x32_bf16(pf, vf, accO[d], 0, 0, 0);
      }
    }
    __syncthreads();
  }

  const int b = bh >> 4, h = bh & 15;
#pragma unroll
  for (int r = 0; r < 4; ++r) {
    float s = l_run[r];
    s += __shfl_xor(s, 1);
    s += __shfl_xor(s, 2);
    s += __shfl_xor(s, 4);
    s += __shfl_xor(s, 8);
    float inv = 1.f / s;
    int q = q0 + wid * 16 + g * 4 + r;
#pragma unroll
    for (int d = 0; d < 4; ++d)
      Ab[(size_t)(b * SEQL + q) * EMB + h * HDIM + d * 16 + lrow] = f2bf(accO[d][r] * inv);
  }
}

extern "C" void kernel_launch(void* const* d_in, const int* in_sizes, int n_in,
                              void* d_out, int out_size, void* d_ws, size_t ws_size,
                              hipStream_t stream) {
  (void)in_sizes; (void)n_in; (void)out_size; (void)ws_size;
  const float* query = (const float*)d_in[0];
  const float* Wq = (const float*)d_in[1];
  const float* bq = (const float*)d_in[2];
  const float* Wk = (const float*)d_in[3];
  const float* bk = (const float*)d_in[4];
  const float* Wv = (const float*)d_in[5];
  const float* bv = (const float*)d_in[6];
  const float* Wo = (const float*)d_in[7];
  const float* bo = (const float*)d_in[8];
  float* out = (float*)d_out;

  const size_t MB = 1u << 20;
  char* ws = (char*)d_ws;
  u16* Xb  = (u16*)(ws);              // 16 MB  (reused as attn output after QKV GEMM)
  u16* Wqb = (u16*)(ws + 16 * MB);
  u16* Wkb = (u16*)(ws + 18 * MB);
  u16* Wvb = (u16*)(ws + 20 * MB);
  u16* Wob = (u16*)(ws + 22 * MB);
  u16* Qbf = (u16*)(ws + 24 * MB);    // [bh][s][d] bf16, 16 MB
  u16* Kbf = (u16*)(ws + 40 * MB);
  u16* Vbf = (u16*)(ws + 56 * MB);
  u16* Ab  = Xb;                      // alias: Xb dead after gemm_qkv

  cvt_kernel<<<4096, 256, 0, stream>>>(query, Xb, MROWS * EMB);
  cvt_w4<<<dim3(512, 4), 256, 0, stream>>>(Wq, Wk, Wv, Wo, Wqb, Wkb, Wvb, Wob);
  gemm_qkv<<<dim3(512, 3), 256, 0, stream>>>(Xb, Wqb, Wkb, Wvb, bq, bk, bv, Qbf, Kbf, Vbf);
  attn_kernel<<<dim3(32, 64), 256, 0, stream>>>(Qbf, Kbf, Vbf, Ab);
  gemm_out<<<512, 256, 0, stream>>>(Ab, Wob, bo, out);
}

// Round 2
// 191.443 us; speedup vs baseline: 2.0173x; 2.0173x over previous
//
#include <hip/hip_runtime.h>
#include <stdint.h>

typedef unsigned short u16;
typedef __attribute__((ext_vector_type(8))) __bf16 bf16x8;
typedef __attribute__((ext_vector_type(4))) float f32x4;

#define SEQL 2048
#define NHEADS 16
#define HDIM 64
#define BSZ 4
#define EMB 1024
#define MROWS (BSZ * SEQL) /* 8192 */

__device__ __forceinline__ u16 f2bf(float f) {
  union { float f; uint32_t u; } v; v.f = f;
  return (u16)((v.u + 0x7fffu + ((v.u >> 16) & 1u)) >> 16);
}

__device__ __forceinline__ void gload_lds16(const u16* g, u16* l) {
  __builtin_amdgcn_global_load_lds(
      (__attribute__((address_space(1))) void*)(g),
      (__attribute__((address_space(3))) void*)(l), 16, 0, 0);
}

__device__ __forceinline__ void cvt8(const float* __restrict__ in, u16* __restrict__ out, int i) {
  float4 a = *(const float4*)(in + i);
  float4 b = *(const float4*)(in + i + 4);
  uint4 o;
  o.x = f2bf(a.x) | ((uint32_t)f2bf(a.y) << 16);
  o.y = f2bf(a.z) | ((uint32_t)f2bf(a.w) << 16);
  o.z = f2bf(b.x) | ((uint32_t)f2bf(b.y) << 16);
  o.w = f2bf(b.z) | ((uint32_t)f2bf(b.w) << 16);
  *(uint4*)(out + i) = o;
}

// ---------------- fp32 -> bf16 conversions ----------------
__global__ void cvt_kernel(const float* __restrict__ in, u16* __restrict__ out, int n) {
  int i = (blockIdx.x * blockDim.x + threadIdx.x) * 8;
  if (i + 8 <= n) cvt8(in, out, i);
}

__global__ void cvt_w4(const float* __restrict__ w0, const float* __restrict__ w1,
                       const float* __restrict__ w2, const float* __restrict__ w3,
                       u16* __restrict__ o0, u16* __restrict__ o1,
                       u16* __restrict__ o2, u16* __restrict__ o3) {
  const float* in = blockIdx.y == 0 ? w0 : blockIdx.y == 1 ? w1 : blockIdx.y == 2 ? w2 : w3;
  u16* out = blockIdx.y == 0 ? o0 : blockIdx.y == 1 ? o1 : blockIdx.y == 2 ? o2 : o3;
  int i = (blockIdx.x * blockDim.x + threadIdx.x) * 8;
  cvt8(in, out, i);
}

// ---------------- GEMM core: C[128x128] = A[128xK] * B[128xK]^T ----------------
__device__ __forceinline__ void gemm_core(const u16* __restrict__ A, const u16* __restrict__ B,
                                          int m0, int n0, u16* As, u16* Bs, f32x4 acc[4][4]) {
  const int tid = threadIdx.x;
  const int lane = tid & 63;
  const int wid = tid >> 6;
  const int wm = wid >> 1, wn = wid & 1;
  const int srow = lane >> 2;
  const int scol = (lane & 3) * 8;
  const int lrow = lane & 15;
  const int kg = (lane >> 4) * 8;

  const u16* Ag0 = A + (size_t)(m0 + wid * 32 + srow) * EMB + scol;
  const u16* Bg0 = B + (size_t)(n0 + wid * 32 + srow) * EMB + scol;
  u16* Al0 = As + (wid * 32 + srow) * 32 + scol;
  u16* Bl0 = Bs + (wid * 32 + srow) * 32 + scol;

  for (int k0 = 0; k0 < EMB; k0 += 32) {
    gload_lds16(Ag0 + k0, Al0);
    gload_lds16(Ag0 + k0 + 16 * EMB, Al0 + 16 * 32);
    gload_lds16(Bg0 + k0, Bl0);
    gload_lds16(Bg0 + k0 + 16 * EMB, Bl0 + 16 * 32);
    __syncthreads();
    bf16x8 af[4], bfr[4];
#pragma unroll
    for (int f = 0; f < 4; ++f) {
      af[f]  = *(const bf16x8*)(As + (wm * 64 + f * 16 + lrow) * 32 + kg);
      bfr[f] = *(const bf16x8*)(Bs + (wn * 64 + f * 16 + lrow) * 32 + kg);
    }
#pragma unroll
    for (int fm = 0; fm < 4; ++fm)
#pragma unroll
      for (int fn = 0; fn < 4; ++fn)
        acc[fm][fn] = __builtin_amdgcn_mfma_f32_16x16x32_bf16(af[fm], bfr[fn], acc[fm][fn], 0, 0, 0);
    __syncthreads();
  }
}

// QKV projection. Q,K written [bh][s][d]; V written TRANSPOSED [bh][d][s].
__global__ __launch_bounds__(256, 2) void gemm_qkv(
    const u16* __restrict__ X,
    const u16* __restrict__ Wq, const u16* __restrict__ Wk, const u16* __restrict__ Wv,
    const float* __restrict__ bq, const float* __restrict__ bk, const float* __restrict__ bv,
    u16* __restrict__ Qb, u16* __restrict__ Kb, u16* __restrict__ Vt) {
  __shared__ u16 As[128 * 32];
  __shared__ u16 Bs[128 * 32];
  const int which = blockIdx.y;
  const u16* W = which == 0 ? Wq : which == 1 ? Wk : Wv;
  const float* bias = which == 0 ? bq : which == 1 ? bk : bv;

  const int mt = blockIdx.x >> 3, nt = blockIdx.x & 7;
  const f32x4 fzero = {0.f, 0.f, 0.f, 0.f};
  f32x4 acc[4][4];
#pragma unroll
  for (int i = 0; i < 4; ++i)
#pragma unroll
    for (int j = 0; j < 4; ++j) acc[i][j] = fzero;

  gemm_core(X, W, mt * 128, nt * 128, As, Bs, acc);

  const int lane = threadIdx.x & 63;
  const int wid = threadIdx.x >> 6;
  const int wm = wid >> 1, wn = wid & 1;
  const int lrow = lane & 15, g = lane >> 4;

  if (which == 2) {
    // V^T epilogue: [bh][d][s], pack 4 consecutive s per uint2
#pragma unroll
    for (int fm = 0; fm < 4; ++fm)
#pragma unroll
      for (int fn = 0; fn < 4; ++fn) {
        int n = nt * 128 + wn * 64 + fn * 16 + lrow;
        float bs = bias[n];
        int h = n >> 6, d = n & 63;
        int m0 = mt * 128 + wm * 64 + fm * 16 + g * 4;
        int b = m0 >> 11, s = m0 & 2047;
        union { u16 s4[4]; uint2 u; } o;
#pragma unroll
        for (int r = 0; r < 4; ++r) o.s4[r] = f2bf(acc[fm][fn][r] + bs);
        *(uint2*)(Vt + ((size_t)(b * NHEADS + h) * HDIM + d) * SEQL + s) = o.u;
      }
  } else {
    u16* Ob = which == 0 ? Qb : Kb;
    const float scale = which == 0 ? 0.125f : 1.0f;
#pragma unroll
    for (int fm = 0; fm < 4; ++fm)
#pragma unroll
      for (int fn = 0; fn < 4; ++fn) {
        int n = nt * 128 + wn * 64 + fn * 16 + lrow;
        float bs = bias[n];
        int h = n >> 6, d = n & 63;
#pragma unroll
        for (int r = 0; r < 4; ++r) {
          int m = mt * 128 + wm * 64 + fm * 16 + g * 4 + r;
          int b = m >> 11, s = m & 2047;
          float v = (acc[fm][fn][r] + bs) * scale;
          Ob[(size_t)((b * NHEADS + h) * SEQL + s) * HDIM + d] = f2bf(v);
        }
      }
  }
}

// Output projection: fp32 result
__global__ __launch_bounds__(256, 2) void gemm_out(
    const u16* __restrict__ Ain, const u16* __restrict__ Wo,
    const float* __restrict__ bo, float* __restrict__ out) {
  __shared__ u16 As[128 * 32];
  __shared__ u16 Bs[128 * 32];
  const int mt = blockIdx.x >> 3, nt = blockIdx.x & 7;
  const f32x4 fzero = {0.f, 0.f, 0.f, 0.f};
  f32x4 acc[4][4];
#pragma unroll
  for (int i = 0; i < 4; ++i)
#pragma unroll
    for (int j = 0; j < 4; ++j) acc[i][j] = fzero;

  gemm_core(Ain, Wo, mt * 128, nt * 128, As, Bs, acc);

  const int lane = threadIdx.x & 63;
  const int wid = threadIdx.x >> 6;
  const int wm = wid >> 1, wn = wid & 1;
  const int lrow = lane & 15, g = lane >> 4;
#pragma unroll
  for (int fm = 0; fm < 4; ++fm)
#pragma unroll
    for (int fn = 0; fn < 4; ++fn) {
      int n = nt * 128 + wn * 64 + fn * 16 + lrow;
      float bs = bo[n];
#pragma unroll
      for (int r = 0; r < 4; ++r) {
        int m = mt * 128 + wm * 64 + fm * 16 + g * 4 + r;
        out[(size_t)m * EMB + n] = acc[fm][fn][r] + bs;
      }
    }
}

// ---------------- causal flash attention, swapped-QK^T, P in registers ----------------
// grid: 2048 blocks = 32 qtiles x 64 bh (interleaved heavy/light). 4 waves x 16 q-rows.
// KV tile = 64, double-buffered LDS, V pre-transposed globally.
__global__ __launch_bounds__(256, 4) void attn2_kernel(
    const u16* __restrict__ Qb, const u16* __restrict__ Kb, const u16* __restrict__ Vt,
    u16* __restrict__ Ab) {
  __shared__ u16 Ks[2][64 * 72];
  __shared__ u16 Vs[2][64 * 72];

  const int bid = blockIdx.x;
  const int grp = bid >> 6;                                  // 0..31
  const int bh  = bid & 63;
  const int qt  = (grp & 1) ? (grp >> 1) : (31 - (grp >> 1)); // heavy/light interleave
  const int q0  = qt * 64;
  const int NT  = qt + 1;

  const int tid = threadIdx.x, lane = tid & 63, wid = tid >> 6;
  const int lrow = lane & 15, g = lane >> 4, kg = g * 8;

  const u16* Qbh = Qb + (size_t)bh * SEQL * HDIM;
  const u16* Kbh = Kb + (size_t)bh * SEQL * HDIM;
  const u16* Vbh = Vt + (size_t)bh * HDIM * SEQL;

  const int qrow = q0 + wid * 16 + lrow;
  const bf16x8 qf0 = *(const bf16x8*)(Qbh + (size_t)qrow * HDIM + kg);
  const bf16x8 qf1 = *(const bf16x8*)(Qbh + (size_t)qrow * HDIM + 32 + kg);

  const int srow = tid >> 3;            // 0..31 (row, +32 for second half)
  const int sc8  = (tid & 7) * 8;       // 16B column chunk

  float m_run = -1e30f, l_run = 0.f;
  const f32x4 fzero = {0.f, 0.f, 0.f, 0.f};
  f32x4 accO[4];
#pragma unroll
  for (int d = 0; d < 4; ++d) accO[d] = fzero;

  // prologue: stage tile 0
  {
    uint4 k0 = *(const uint4*)(Kbh + (size_t)srow * HDIM + sc8);
    uint4 k1 = *(const uint4*)(Kbh + (size_t)(srow + 32) * HDIM + sc8);
    uint4 v0 = *(const uint4*)(Vbh + (size_t)srow * SEQL + sc8);
    uint4 v1 = *(const uint4*)(Vbh + (size_t)(srow + 32) * SEQL + sc8);
    *(uint4*)(&Ks[0][srow * 72 + sc8]) = k0;
    *(uint4*)(&Ks[0][(srow + 32) * 72 + sc8]) = k1;
    *(uint4*)(&Vs[0][srow * 72 + sc8]) = v0;
    *(uint4*)(&Vs[0][(srow + 32) * 72 + sc8]) = v1;
  }
  __syncthreads();

  const int q_max = q0 + wid * 16 + 15;

  for (int t = 0; t < NT; ++t) {
    const int cur = t & 1;
    const int kv0 = t * 64;
    const bool pf = (t + 1 < NT);
    uint4 k0, k1, v0, v1;
    if (pf) {  // issue next-tile loads early; latency hides under compute
      const int kvn = kv0 + 64;
      k0 = *(const uint4*)(Kbh + (size_t)(kvn + srow) * HDIM + sc8);
      k1 = *(const uint4*)(Kbh + (size_t)(kvn + srow + 32) * HDIM + sc8);
      v0 = *(const uint4*)(Vbh + (size_t)srow * SEQL + kvn + sc8);
      v1 = *(const uint4*)(Vbh + (size_t)(srow + 32) * SEQL + kvn + sc8);
    }

    if (kv0 <= q_max) {
      // S^T = K Q^T : lane holds S[kv = kv0 + kb*16 + g*4 + r][q = qrow]
      f32x4 sacc[4];
#pragma unroll
      for (int kb = 0; kb < 4; ++kb) {
        bf16x8 kfa = *(const bf16x8*)(&Ks[cur][(kb * 16 + lrow) * 72 + kg]);
        bf16x8 kfb = *(const bf16x8*)(&Ks[cur][(kb * 16 + lrow) * 72 + 32 + kg]);
        f32x4 z = fzero;
        z = __builtin_amdgcn_mfma_f32_16x16x32_bf16(kfa, qf0, z, 0, 0, 0);
        z = __builtin_amdgcn_mfma_f32_16x16x32_bf16(kfb, qf1, z, 0, 0, 0);
        sacc[kb] = z;
      }

      if (kv0 + 63 > q0 + wid * 16) {  // causal mask (diagonal tiles only)
#pragma unroll
        for (int kb = 0; kb < 4; ++kb)
#pragma unroll
          for (int r = 0; r < 4; ++r)
            if (kv0 + kb * 16 + g * 4 + r > qrow) sacc[kb][r] = -1e30f;
      }

      // online softmax: row q = lrow is lane-local up to the 4 g-groups
      float mx = sacc[0][0];
#pragma unroll
      for (int kb = 0; kb < 4; ++kb)
#pragma unroll
        for (int r = 0; r < 4; ++r) mx = fmaxf(mx, sacc[kb][r]);
      mx = fmaxf(mx, __shfl_xor(mx, 16));
      mx = fmaxf(mx, __shfl_xor(mx, 32));
      const float mnew = fmaxf(m_run, mx);
      const float sc = __expf(m_run - mnew);
      m_run = mnew;
      l_run *= sc;
#pragma unroll
      for (int d = 0; d < 4; ++d) accO[d] *= sc;

      bf16x8 pa[2];
      float ls = 0.f;
#pragma unroll
      for (int kb = 0; kb < 4; ++kb)
#pragma unroll
        for (int r = 0; r < 4; ++r) {
          float p = __expf(sacc[kb][r] - mnew);
          ls += p;
          pa[kb >> 1][(kb & 1) * 4 + r] = (__bf16)p;
        }
      l_run += ls;

      // PV: O^T-form mfma(V^T rows, P rows) -> lane holds O[q=lrow][d=dblk*16+g*4+r]
#pragma unroll
      for (int ks = 0; ks < 2; ++ks)
#pragma unroll
        for (int d = 0; d < 4; ++d) {
          const u16* vb = &Vs[cur][(d * 16 + lrow) * 72 + ks * 32 + g * 4];
          union { ushort4 h[2]; bf16x8 v; } vf;
          vf.h[0] = *(const ushort4*)(vb);
          vf.h[1] = *(const ushort4*)(vb + 16);
          accO[d] = __builtin_amdgcn_mfma_f32_16x16x32_bf16(vf.v, pa[ks], accO[d], 0, 0, 0);
        }
    }

    if (pf) {  // publish next tile into the other buffer
      const int nb = cur ^ 1;
      *(uint4*)(&Ks[nb][srow * 72 + sc8]) = k0;
      *(uint4*)(&Ks[nb][(srow + 32) * 72 + sc8]) = k1;
      *(uint4*)(&Vs[nb][srow * 72 + sc8]) = v0;
      *(uint4*)(&Vs[nb][(srow + 32) * 72 + sc8]) = v1;
    }
    __syncthreads();
  }

  float l = l_run;
  l += __shfl_xor(l, 16);
  l += __shfl_xor(l, 32);
  const float inv = 1.f / l;
  const int b = bh >> 4, h = bh & 15;
#pragma unroll
  for (int d = 0; d < 4; ++d) {
    union { u16 s4[4]; uint2 u; } o;
#pragma unroll
    for (int r = 0; r < 4; ++r) o.s4[r] = f2bf(accO[d][r] * inv);
    *(uint2*)(Ab + (size_t)(b * SEQL + qrow) * EMB + h * HDIM + d * 16 + g * 4) = o.u;
  }
}

extern "C" void kernel_launch(void* const* d_in, const int* in_sizes, int n_in,
                              void* d_out, int out_size, void* d_ws, size_t ws_size,
                              hipStream_t stream) {
  (void)in_sizes; (void)n_in; (void)out_size; (void)ws_size;
  const float* query = (const float*)d_in[0];
  const float* Wq = (const float*)d_in[1];
  const float* bq = (const float*)d_in[2];
  const float* Wk = (const float*)d_in[3];
  const float* bk = (const float*)d_in[4];
  const float* Wv = (const float*)d_in[5];
  const float* bv = (const float*)d_in[6];
  const float* Wo = (const float*)d_in[7];
  const float* bo = (const float*)d_in[8];
  float* out = (float*)d_out;

  const size_t MB = 1u << 20;
  char* ws = (char*)d_ws;
  u16* Xb  = (u16*)(ws);              // 16 MB (reused as attn output)
  u16* Wqb = (u16*)(ws + 16 * MB);
  u16* Wkb = (u16*)(ws + 18 * MB);
  u16* Wvb = (u16*)(ws + 20 * MB);
  u16* Wob = (u16*)(ws + 22 * MB);
  u16* Qbf = (u16*)(ws + 24 * MB);    // [bh][s][d] bf16
  u16* Kbf = (u16*)(ws + 40 * MB);    // [bh][s][d] bf16
  u16* Vtg = (u16*)(ws + 56 * MB);    // [bh][d][s] bf16 (transposed)
  u16* Ab  = Xb;

  cvt_kernel<<<4096, 256, 0, stream>>>(query, Xb, MROWS * EMB);
  cvt_w4<<<dim3(512, 4), 256, 0, stream>>>(Wq, Wk, Wv, Wo, Wqb, Wkb, Wvb, Wob);
  gemm_qkv<<<dim3(512, 3), 256, 0, stream>>>(Xb, Wqb, Wkb, Wvb, bq, bk, bv, Qbf, Kbf, Vtg);
  attn2_kernel<<<2048, 256, 0, stream>>>(Qbf, Kbf, Vtg, Ab);
  gemm_out<<<512, 256, 0, stream>>>(Ab, Wob, bo, out);
}